// Round 7
// baseline (285.650 us; speedup 1.0000x reference)
//
#include <hip/hip_runtime.h>

#define TOKENS 16384
#define KDIM   2048
#define NEXP   64
#define TOPK   6
#define WSPLIT 4                 // waves per block (in-block K-split)
#define KSPB   2                 // cross-block K-split
#define SPW    8                 // 32-k steps per wave (64 / (WSPLIT*KSPB))

typedef __attribute__((ext_vector_type(8))) short    short8;
typedef __attribute__((ext_vector_type(4))) float    f32x4;
typedef __attribute__((ext_vector_type(4))) unsigned uint4v;

__device__ __forceinline__ unsigned short bf16rn(float f, float* back) {
  unsigned u = __builtin_bit_cast(unsigned, f);
  unsigned short h = (unsigned short)((u + 0x7FFFu + ((u >> 16) & 1u)) >> 16);
  *back = __builtin_bit_cast(float, (unsigned)h << 16);
  return h;
}

// Kernel 0: split W[2048][64] into 3 bf16 limbs packed in MFMA B-fragment
// order pw[s][nt][lv][lane][8hw], lane=(q=(k>>3)&3)*16+(n&15). (verified R5/R6)
__global__ __launch_bounds__(256)
void split_w(const float* __restrict__ wg, unsigned short* __restrict__ pw) {
  const int t = blockIdx.x * 256 + threadIdx.x;   // 131072 threads
  const int n = t & 63, k = t >> 6;
  const float w = wg[(size_t)k * NEXP + n];
  float b0, b1, b2;
  const unsigned short h = bf16rn(w, &b0);
  const float r1 = w - b0;
  const unsigned short m = bf16rn(r1, &b1);
  const float r2 = r1 - b1;
  const unsigned short l = bf16rn(r2, &b2);
  const int s = k >> 5, q = (k >> 3) & 3, j = k & 7;
  const int lane = q * 16 + (n & 15), nt = n >> 4;
  const size_t base = ((size_t)(s * 12 + nt * 3) * 64 + lane) * 8 + j;
  pw[base]        = h;
  pw[base + 512]  = m;
  pw[base + 1024] = l;
}

// Kernel 1: 3-limb bf16 MFMA partial GEMM. Grid (1024 token-tiles, 2 K-halves)
// = 2048 blocks = 8 blocks/CU = 32 waves/CU. Wave = 16 tokens x 64 experts x
// 256 k (8 steps). No barriers/LDS in K-loop; B coalesced from L2-resident pw.
__global__ __launch_bounds__(256, 8)
void gemm_part(const float* __restrict__ x, const unsigned short* __restrict__ pw,
               float* __restrict__ part) {
  __shared__ float red[WSPLIT * 4 * 64 * 4];   // 16 KB

  const int t    = threadIdx.x;
  const int wave = t >> 6;
  const int lane = t & 63;
  const int q    = lane >> 4;
  const int c    = lane & 15;

  const int s0 = blockIdx.y * (WSPLIT * SPW) + wave * SPW;    // first 32-k step
  const size_t m_glob = (size_t)blockIdx.x * 16 + c;          // A row (m=lane&15)
  const float*  ap = x + m_glob * KDIM + s0 * 32 + q * 8;
  const short8* bp = (const short8*)pw + (size_t)(s0 * 12) * 64 + lane;

  f32x4 acc[4];
#pragma unroll
  for (int nt = 0; nt < 4; ++nt) acc[nt] = (f32x4){0.f, 0.f, 0.f, 0.f};

  uint4v a0 = *(const uint4v*)(ap);
  uint4v a1 = *(const uint4v*)(ap + 4);

#pragma unroll 1
  for (int si = 0; si < SPW; ++si) {
    uint4v n0 = a0, n1 = a1;
    if (si + 1 < SPW) {
      n0 = *(const uint4v*)(ap + (si + 1) * 32);
      n1 = *(const uint4v*)(ap + (si + 1) * 32 + 4);
    }

    const short8* bps  = bp + si * 768;
    const short8* bps2 = bps + 384;
    short8 B[4][3];
#pragma unroll
    for (int nt = 0; nt < 2; ++nt)
#pragma unroll
      for (int lv = 0; lv < 3; ++lv) {
        B[nt][lv]     = bps[(nt * 3 + lv) * 64];
        B[nt + 2][lv] = bps2[(nt * 3 + lv) * 64];
      }

    // truncation limb-split of A (exact limbs; dropped terms ~2^-25 rel)
    const unsigned u[8] = {a0.x, a0.y, a0.z, a0.w, a1.x, a1.y, a1.z, a1.w};
    unsigned ph[4], pm[4], pl[4];
#pragma unroll
    for (int p = 0; p < 4; ++p) {
      const unsigned ulo = u[2 * p], uhi = u[2 * p + 1];
      ph[p] = (uhi & 0xFFFF0000u) | (ulo >> 16);
      const float flo = __builtin_bit_cast(float, ulo);
      const float fhi = __builtin_bit_cast(float, uhi);
      const float r1lo = flo - __builtin_bit_cast(float, ulo & 0xFFFF0000u);
      const float r1hi = fhi - __builtin_bit_cast(float, uhi & 0xFFFF0000u);
      const unsigned v1lo = __builtin_bit_cast(unsigned, r1lo);
      const unsigned v1hi = __builtin_bit_cast(unsigned, r1hi);
      pm[p] = (v1hi & 0xFFFF0000u) | (v1lo >> 16);
      const float r2lo = r1lo - __builtin_bit_cast(float, v1lo & 0xFFFF0000u);
      const float r2hi = r1hi - __builtin_bit_cast(float, v1hi & 0xFFFF0000u);
      pl[p] = (__builtin_bit_cast(unsigned, r2hi) & 0xFFFF0000u) |
              (__builtin_bit_cast(unsigned, r2lo) >> 16);
    }
    const short8 Ah = __builtin_bit_cast(short8, (uint4v){ph[0], ph[1], ph[2], ph[3]});
    const short8 Am = __builtin_bit_cast(short8, (uint4v){pm[0], pm[1], pm[2], pm[3]});
    const short8 Al = __builtin_bit_cast(short8, (uint4v){pl[0], pl[1], pl[2], pl[3]});

#pragma unroll
    for (int nt = 0; nt < 4; ++nt) {
      acc[nt] = __builtin_amdgcn_mfma_f32_16x16x32_bf16(Ah, B[nt][0], acc[nt], 0, 0, 0);
      acc[nt] = __builtin_amdgcn_mfma_f32_16x16x32_bf16(Ah, B[nt][1], acc[nt], 0, 0, 0);
      acc[nt] = __builtin_amdgcn_mfma_f32_16x16x32_bf16(Am, B[nt][0], acc[nt], 0, 0, 0);
      acc[nt] = __builtin_amdgcn_mfma_f32_16x16x32_bf16(Am, B[nt][1], acc[nt], 0, 0, 0);
      acc[nt] = __builtin_amdgcn_mfma_f32_16x16x32_bf16(Ah, B[nt][2], acc[nt], 0, 0, 0);
      acc[nt] = __builtin_amdgcn_mfma_f32_16x16x32_bf16(Al, B[nt][0], acc[nt], 0, 0, 0);
    }
    a0 = n0; a1 = n1;
  }

  // in-block combine of the 4 wave-partials; wave 0 stores to part
#pragma unroll
  for (int nt = 0; nt < 4; ++nt)
    *(f32x4*)(red + ((wave * 4 + nt) * 64 + lane) * 4) = acc[nt];
  __syncthreads();

  if (wave == 0) {
    f32x4 S[4];
#pragma unroll
    for (int nt = 0; nt < 4; ++nt) {
      S[nt] = acc[nt];
#pragma unroll
      for (int w = 1; w < WSPLIT; ++w)
        S[nt] += *(const f32x4*)(red + ((w * 4 + nt) * 64 + lane) * 4);
    }
    // C layout: token = q*4+r, expert = nt*16+c
    float* pb = part + ((size_t)blockIdx.y * TOKENS + blockIdx.x * 16) * NEXP;
#pragma unroll
    for (int r = 0; r < 4; ++r)
#pragma unroll
      for (int nt = 0; nt < 4; ++nt)
        pb[(q * 4 + r) * NEXP + nt * 16 + c] = S[nt][r];
  }
}

// Kernel 2: 16 lanes/token, 4 experts/lane; sum 2 partials, softmax, top-6
// with jax tie-break (equal -> lower index). (structure verified R2-R4)
__global__ __launch_bounds__(256)
void moe_softmax_topk(const float* __restrict__ part, float* __restrict__ out) {
  const int lane = threadIdx.x & 63;
  const int wid  = threadIdx.x >> 6;
  const int sub  = lane & 15;
  const int tok  = blockIdx.x * 16 + wid * 4 + (lane >> 4);

  float v[4] = {0.f, 0.f, 0.f, 0.f};
#pragma unroll
  for (int ks = 0; ks < KSPB; ++ks) {
    const float4 p = *(const float4*)(part + ((size_t)ks * TOKENS + tok) * NEXP + sub * 4);
    v[0] += p.x; v[1] += p.y; v[2] += p.z; v[3] += p.w;
  }

  float m = fmaxf(fmaxf(v[0], v[1]), fmaxf(v[2], v[3]));
#pragma unroll
  for (int off = 1; off < 16; off <<= 1) m = fmaxf(m, __shfl_xor(m, off));
  float e0 = expf(v[0] - m), e1 = expf(v[1] - m), e2 = expf(v[2] - m), e3 = expf(v[3] - m);
  float sd = e0 + e1 + e2 + e3;
#pragma unroll
  for (int off = 1; off < 16; off <<= 1) sd += __shfl_xor(sd, off);
  v[0] = e0 / sd; v[1] = e1 / sd; v[2] = e2 / sd; v[3] = e3 / sd;

  float resv = 0.f; int resi = 0;
#pragma unroll
  for (int r = 0; r < TOPK; ++r) {
    float bv = v[0]; int bi = sub * 4;
#pragma unroll
    for (int j = 1; j < 4; ++j)
      if (v[j] > bv) { bv = v[j]; bi = sub * 4 + j; }   // strict >: low idx on tie
#pragma unroll
    for (int off = 1; off < 16; off <<= 1) {
      const float ov = __shfl_xor(bv, off);
      const int   oi = __shfl_xor(bi, off);
      if (ov > bv || (ov == bv && oi < bi)) { bv = ov; bi = oi; }
    }
    if (sub == r) { resv = bv; resi = bi; }
    if ((bi >> 2) == sub) v[bi & 3] = -1.f;
  }

  if (sub < TOPK) {
    out[(size_t)tok * TOPK + sub] = (float)resi;
    out[(size_t)TOKENS * TOPK + (size_t)tok * TOPK + sub] = resv;
  }
}

extern "C" void kernel_launch(void* const* d_in, const int* in_sizes, int n_in,
                              void* d_out, int out_size, void* d_ws, size_t ws_size,
                              hipStream_t stream) {
  const float* x  = (const float*)d_in[0];
  const float* wg = (const float*)d_in[1];
  float* out = (float*)d_out;
  unsigned short* pw = (unsigned short*)d_ws;                    // 786432 B
  float* part = (float*)((char*)d_ws + 786432);                  // 8 MB

  split_w<<<dim3((KDIM * NEXP) / 256), dim3(256), 0, stream>>>(wg, pw);
  gemm_part<<<dim3(TOKENS / 16, KSPB), dim3(256), 0, stream>>>(x, pw, part);
  moe_softmax_topk<<<dim3(TOKENS / 16), dim3(256), 0, stream>>>(part, out);
}